// Round 1
// baseline (426.802 us; speedup 1.0000x reference)
//
#include <hip/hip_runtime.h>
#include <math.h>

#define B_   256
#define V_   6890
#define NJ_  24
#define NB_  10
#define NP_  207
#define NJR_ 43
#define V3_  20670   // V*3

// ws layout (in floats)
#define JST_OFF 0        // 24*33 = 792    (J_template + J_shape, layout [j][33])
#define PF_OFF  1024     // 256*207 = 52992 (pose_feature)
#define A_OFF   55296    // 256*24*12 = 73728 (A matrices, rows 0..2 of 4x4)
// total 129024 floats = 516 KB

// ---------------------------------------------------------------------------
// K0: Jst[j][0..2] = sum_v JR[j,v]*v_template[v,d]
//     Jst[j][3+k*3+d] = sum_v JR[j,v]*shapedirs[k, v*3+d]
// ---------------------------------------------------------------------------
__global__ __launch_bounds__(256) void k_jst(const float* __restrict__ JR,
                                             const float* __restrict__ vtm,
                                             const float* __restrict__ sd,
                                             float* __restrict__ Jst)
{
    const int j = blockIdx.x;
    const int tid = threadIdx.x;
    float acc[33];
#pragma unroll
    for (int c = 0; c < 33; c++) acc[c] = 0.f;

    for (int v = tid; v < V_; v += 256) {
        float jr = JR[(size_t)j * V_ + v];
        const float* tv = vtm + (size_t)v * 3;
        acc[0] += jr * tv[0];
        acc[1] += jr * tv[1];
        acc[2] += jr * tv[2];
#pragma unroll
        for (int k = 0; k < 10; k++) {
            const float* sp = sd + (size_t)k * V3_ + (size_t)v * 3;
            acc[3 + k*3 + 0] += jr * sp[0];
            acc[3 + k*3 + 1] += jr * sp[1];
            acc[3 + k*3 + 2] += jr * sp[2];
        }
    }
    // wave (64-lane) butterfly reduce, then cross-wave via LDS
#pragma unroll
    for (int c = 0; c < 33; c++) {
        float s = acc[c];
#pragma unroll
        for (int off = 32; off > 0; off >>= 1) s += __shfl_xor(s, off);
        acc[c] = s;
    }
    __shared__ float red[4][33];
    const int wv = tid >> 6, ln = tid & 63;
    if (ln == 0) {
#pragma unroll
        for (int c = 0; c < 33; c++) red[wv][c] = acc[c];
    }
    __syncthreads();
    if (tid < 33)
        Jst[j * 33 + tid] = red[0][tid] + red[1][tid] + red[2][tid] + red[3][tid];
}

// ---------------------------------------------------------------------------
// K1: per-batch rodrigues + kinematic chain.  32 threads/block (1 batch per
// thread), chain state in LDS (stride-32 layout -> conflict-free).
// Writes pose_feature (B x 207) and A (B x 24 x 12).
// ---------------------------------------------------------------------------
__global__ void k_chain(const float* __restrict__ beta,
                        const float* __restrict__ theta,
                        const float* __restrict__ Jst,
                        float* __restrict__ pf,
                        float* __restrict__ Aout)
{
    __shared__ float resL[24 * 12 * 32];  // [j][e 0..11][t]
    __shared__ float JL[24 * 3 * 32];     // [j][d][t]
    const int t = threadIdx.x;            // 0..31
    const int b = blockIdx.x * 32 + t;

    float bet[10];
#pragma unroll
    for (int k = 0; k < 10; k++) bet[k] = beta[b * 10 + k];

    // J[b,j,d] = J_template + beta . J_shape
#pragma unroll
    for (int j = 0; j < 24; j++) {
#pragma unroll
        for (int d = 0; d < 3; d++) {
            float s = Jst[j * 33 + d];
#pragma unroll
            for (int k = 0; k < 10; k++) s += bet[k] * Jst[j * 33 + 3 + k * 3 + d];
            JL[(j * 3 + d) * 32 + t] = s;
        }
    }

    const int par[24] = {0,0,0,0,1,2,3,4,5,6,7,8,9,9,9,12,13,14,16,17,18,19,20,21};

#pragma unroll
    for (int j = 0; j < 24; j++) {
        float t0 = theta[b * 72 + 3 * j + 0];
        float t1 = theta[b * 72 + 3 * j + 1];
        float t2 = theta[b * 72 + 3 * j + 2];
        float e0 = t0 + 1e-8f, e1 = t1 + 1e-8f, e2 = t2 + 1e-8f;
        float ang = sqrtf(e0 * e0 + e1 * e1 + e2 * e2);
        float inva = 1.0f / ang;
        float r0 = t0 * inva, r1 = t1 * inva, r2 = t2 * inva;
        float h = 0.5f * ang;
        float qw = cosf(h), sh = sinf(h);
        float qx = sh * r0, qy = sh * r1, qz = sh * r2;
        float qn = sqrtf(qw * qw + qx * qx + qy * qy + qz * qz);
        float inq = 1.0f / qn;
        qw *= inq; qx *= inq; qy *= inq; qz *= inq;
        float R[9];
        R[0] = 1.f - 2.f * (qy * qy + qz * qz);
        R[1] = 2.f * (qx * qy - qw * qz);
        R[2] = 2.f * (qx * qz + qw * qy);
        R[3] = 2.f * (qx * qy + qw * qz);
        R[4] = 1.f - 2.f * (qx * qx + qz * qz);
        R[5] = 2.f * (qy * qz - qw * qx);
        R[6] = 2.f * (qx * qz - qw * qy);
        R[7] = 2.f * (qy * qz + qw * qx);
        R[8] = 1.f - 2.f * (qx * qx + qy * qy);

        if (j == 0) {
            // root_R = R @ diag(1,-1,-1); res0 = [root_R | J0]
#pragma unroll
            for (int m = 0; m < 3; m++) {
                resL[(0 * 12 + m * 4 + 0) * 32 + t] = R[m * 3 + 0];
                resL[(0 * 12 + m * 4 + 1) * 32 + t] = -R[m * 3 + 1];
                resL[(0 * 12 + m * 4 + 2) * 32 + t] = -R[m * 3 + 2];
                resL[(0 * 12 + m * 4 + 3) * 32 + t] = JL[(0 * 3 + m) * 32 + t];
            }
        } else {
#pragma unroll
            for (int e = 0; e < 9; e++)
                pf[b * 207 + (j - 1) * 9 + e] = R[e] - ((e == 0 || e == 4 || e == 8) ? 1.f : 0.f);
            const int p = par[j];
            float tx = JL[(j * 3 + 0) * 32 + t] - JL[(p * 3 + 0) * 32 + t];
            float ty = JL[(j * 3 + 1) * 32 + t] - JL[(p * 3 + 1) * 32 + t];
            float tz = JL[(j * 3 + 2) * 32 + t] - JL[(p * 3 + 2) * 32 + t];
#pragma unroll
            for (int m = 0; m < 3; m++) {
                float pm0 = resL[(p * 12 + m * 4 + 0) * 32 + t];
                float pm1 = resL[(p * 12 + m * 4 + 1) * 32 + t];
                float pm2 = resL[(p * 12 + m * 4 + 2) * 32 + t];
                float pm3 = resL[(p * 12 + m * 4 + 3) * 32 + t];
                resL[(j * 12 + m * 4 + 0) * 32 + t] = pm0 * R[0] + pm1 * R[3] + pm2 * R[6];
                resL[(j * 12 + m * 4 + 1) * 32 + t] = pm0 * R[1] + pm1 * R[4] + pm2 * R[7];
                resL[(j * 12 + m * 4 + 2) * 32 + t] = pm0 * R[2] + pm1 * R[5] + pm2 * R[8];
                resL[(j * 12 + m * 4 + 3) * 32 + t] = pm0 * tx + pm1 * ty + pm2 * tz + pm3;
            }
        }
    }

    // A[b,j] rows 0..2: cols0..2 = res, col3 = res_t - res_R . J[j]
#pragma unroll
    for (int j = 0; j < 24; j++) {
        float Jx = JL[(j * 3 + 0) * 32 + t];
        float Jy = JL[(j * 3 + 1) * 32 + t];
        float Jz = JL[(j * 3 + 2) * 32 + t];
#pragma unroll
        for (int m = 0; m < 3; m++) {
            float c0 = resL[(j * 12 + m * 4 + 0) * 32 + t];
            float c1 = resL[(j * 12 + m * 4 + 1) * 32 + t];
            float c2 = resL[(j * 12 + m * 4 + 2) * 32 + t];
            float c3 = resL[(j * 12 + m * 4 + 3) * 32 + t];
            float* ap = Aout + (size_t)(b * 24 + j) * 12 + m * 4;
            ap[0] = c0; ap[1] = c1; ap[2] = c2;
            ap[3] = c3 - (c0 * Jx + c1 * Jy + c2 * Jz);
        }
    }
}

// ---------------------------------------------------------------------------
// K2: v_posed[b,i] = vt[i] + beta[b]·sd[:,i] + pf[b]·pd[:,i]
// Register-tiled fp32 GEMM: block = 64 batches x 128 cols, thread = 8b x 4i.
// Result written into d_out verts region (overwritten in-place by K3).
// ---------------------------------------------------------------------------
__global__ __launch_bounds__(256) void k_vposed(const float* __restrict__ beta,
                                                const float* __restrict__ vt,
                                                const float* __restrict__ sd,
                                                const float* __restrict__ pd,
                                                const float* __restrict__ pf,
                                                float* __restrict__ vp)
{
    __shared__ __align__(16) float coefT[217 * 64];  // [k][bb]
    const int tid = threadIdx.x;
    const int bblk = blockIdx.y * 64;
    for (int idx = tid; idx < 217 * 64; idx += 256) {
        int k = idx >> 6, bb = idx & 63, b = bblk + bb;
        coefT[idx] = (k < 10) ? beta[b * 10 + k] : pf[b * 207 + (k - 10)];
    }
    __syncthreads();

    const int tx = tid & 31, ty = tid >> 5;
    int ibase = blockIdx.x * 128 + tx * 4;
    if (ibase > V3_ - 4) ibase = V3_ - 4;  // clamp: duplicate identical writes, benign

    float acc[8][4];
#pragma unroll
    for (int i = 0; i < 8; i++)
#pragma unroll
        for (int q = 0; q < 4; q++) acc[i][q] = 0.f;

#define K2_STEP(DR, CIDX)                                                     \
    {                                                                         \
        const float* Dr_ = (DR);                                              \
        float2 bA = *(const float2*)(Dr_);                                    \
        float2 bB = *(const float2*)(Dr_ + 2);                                \
        const float4* cf = (const float4*)(coefT + (CIDX) * 64 + ty * 8);     \
        float4 a0 = cf[0], a1 = cf[1];                                        \
        float av[8] = {a0.x, a0.y, a0.z, a0.w, a1.x, a1.y, a1.z, a1.w};       \
        float bv[4] = {bA.x, bA.y, bB.x, bB.y};                               \
        _Pragma("unroll") for (int ii = 0; ii < 8; ii++)                      \
            _Pragma("unroll") for (int qq = 0; qq < 4; qq++)                  \
                acc[ii][qq] += av[ii] * bv[qq];                               \
    }

    for (int k = 0; k < 10; k++)  K2_STEP(sd + (size_t)k * V3_ + ibase, k)
    for (int p = 0; p < 207; p++) K2_STEP(pd + (size_t)p * V3_ + ibase, 10 + p)
#undef K2_STEP

    float2 vA = *(const float2*)(vt + ibase);
    float2 vB = *(const float2*)(vt + ibase + 2);
#pragma unroll
    for (int i = 0; i < 8; i++) {
        int b = bblk + ty * 8 + i;
        float* o = vp + (size_t)b * V3_ + ibase;
        float2 o0 = {acc[i][0] + vA.x, acc[i][1] + vA.y};
        float2 o1 = {acc[i][2] + vB.x, acc[i][3] + vB.y};
        *(float2*)o = o0;
        *(float2*)(o + 2) = o1;
    }
}

// ---------------------------------------------------------------------------
// K3: skinning, in place.  weights is batch-broadcast -> read slice [0,:,:].
// ---------------------------------------------------------------------------
__global__ __launch_bounds__(256) void k_skin(const float* __restrict__ w0,
                                              const float* __restrict__ A,
                                              float* __restrict__ verts)
{
    __shared__ __align__(16) float AL[288];  // A[b] : 24 joints x 12
    const int tid = threadIdx.x;
    const int b = blockIdx.y;
    for (int i = tid; i < 288; i += 256) AL[i] = A[(size_t)b * 288 + i];
    __syncthreads();

#pragma unroll
    for (int rep = 0; rep < 2; rep++) {
        int v = blockIdx.x * 512 + rep * 256 + tid;
        if (v >= V_) continue;
        float wr[24];
        const float4* wp = (const float4*)(w0 + (size_t)v * 24);
#pragma unroll
        for (int q = 0; q < 6; q++) {
            float4 f = wp[q];
            wr[q * 4 + 0] = f.x; wr[q * 4 + 1] = f.y;
            wr[q * 4 + 2] = f.z; wr[q * 4 + 3] = f.w;
        }
        float T[12];
#pragma unroll
        for (int e = 0; e < 12; e++) T[e] = 0.f;
#pragma unroll
        for (int j = 0; j < 24; j++) {
            const float4* a4 = (const float4*)(AL + j * 12);
            float4 a0 = a4[0], a1 = a4[1], a2 = a4[2];
            float wj = wr[j];
            T[0] += wj * a0.x; T[1] += wj * a0.y; T[2]  += wj * a0.z; T[3]  += wj * a0.w;
            T[4] += wj * a1.x; T[5] += wj * a1.y; T[6]  += wj * a1.z; T[7]  += wj * a1.w;
            T[8] += wj * a2.x; T[9] += wj * a2.y; T[10] += wj * a2.z; T[11] += wj * a2.w;
        }
        float* pv = verts + (size_t)b * V3_ + (size_t)v * 3;
        float p0 = pv[0], p1 = pv[1], p2 = pv[2];
        pv[0] = T[0] * p0 + T[1] * p1 + T[2]  * p2 + T[3];
        pv[1] = T[4] * p0 + T[5] * p1 + T[6]  * p2 + T[7];
        pv[2] = T[8] * p0 + T[9] * p1 + T[10] * p2 + T[11];
    }
}

// ---------------------------------------------------------------------------
// K4: joints[b,jr,d] = sum_v jreg[jr,v] * verts[b,v,d]
// block = 4 batches x 8 regressor rows, 96 accumulators/thread.
// ---------------------------------------------------------------------------
__global__ __launch_bounds__(256) void k_joints(const float* __restrict__ jreg,
                                                const float* __restrict__ verts,
                                                float* __restrict__ joints)
{
    const int tid = threadIdx.x;
    const int b0 = blockIdx.x * 4;
    const int jr0 = blockIdx.y * 8;
    float acc[96];
#pragma unroll
    for (int c = 0; c < 96; c++) acc[c] = 0.f;

    for (int v = tid; v < V_; v += 256) {
        float jr[8];
#pragma unroll
        for (int q = 0; q < 8; q++) {
            int j = jr0 + q;
            jr[q] = (j < NJR_) ? jreg[(size_t)j * V_ + v] : 0.f;
        }
#pragma unroll
        for (int i = 0; i < 4; i++) {
            const float* pv = verts + (size_t)(b0 + i) * V3_ + (size_t)v * 3;
            float p0 = pv[0], p1 = pv[1], p2 = pv[2];
#pragma unroll
            for (int q = 0; q < 8; q++) {
                acc[q * 12 + i * 3 + 0] += jr[q] * p0;
                acc[q * 12 + i * 3 + 1] += jr[q] * p1;
                acc[q * 12 + i * 3 + 2] += jr[q] * p2;
            }
        }
    }
#pragma unroll
    for (int c = 0; c < 96; c++) {
        float s = acc[c];
#pragma unroll
        for (int off = 32; off > 0; off >>= 1) s += __shfl_xor(s, off);
        acc[c] = s;
    }
    __shared__ float red[4][96];
    const int wv = tid >> 6, ln = tid & 63;
    if (ln == 0) {
#pragma unroll
        for (int c = 0; c < 96; c++) red[wv][c] = acc[c];
    }
    __syncthreads();
    if (tid < 96) {
        float s = red[0][tid] + red[1][tid] + red[2][tid] + red[3][tid];
        int q = tid / 12, rem = tid % 12, i = rem / 3, d = rem % 3;
        int j = jr0 + q;
        if (j < NJR_) joints[(size_t)(b0 + i) * (NJR_ * 3) + j * 3 + d] = s;
    }
}

extern "C" void kernel_launch(void* const* d_in, const int* in_sizes, int n_in,
                              void* d_out, int out_size, void* d_ws, size_t ws_size,
                              hipStream_t stream)
{
    const float* beta  = (const float*)d_in[0];
    const float* theta = (const float*)d_in[1];
    const float* vtm   = (const float*)d_in[2];
    const float* sd    = (const float*)d_in[3];
    const float* pd    = (const float*)d_in[4];
    const float* JR    = (const float*)d_in[5];
    const float* jreg  = (const float*)d_in[6];
    const float* wts   = (const float*)d_in[7];  // batch-broadcast: use slice [0]

    float* out = (float*)d_out;
    float* ws  = (float*)d_ws;
    float* Jst = ws + JST_OFF;
    float* pf  = ws + PF_OFF;
    float* A   = ws + A_OFF;
    float* verts  = out;                       // also holds v_posed pre-skinning
    float* joints = out + (size_t)B_ * V3_;

    hipLaunchKernelGGL(k_jst,    dim3(24),      dim3(256), 0, stream, JR, vtm, sd, Jst);
    hipLaunchKernelGGL(k_chain,  dim3(8),       dim3(32),  0, stream, beta, theta, Jst, pf, A);
    hipLaunchKernelGGL(k_vposed, dim3(162, 4),  dim3(256), 0, stream, beta, vtm, sd, pd, pf, verts);
    hipLaunchKernelGGL(k_skin,   dim3(14, 256), dim3(256), 0, stream, wts, A, verts);
    hipLaunchKernelGGL(k_joints, dim3(64, 6),   dim3(256), 0, stream, jreg, verts, joints);
}